// Round 1
// baseline (184.243 us; speedup 1.0000x reference)
//
#include <hip/hip_runtime.h>

// Problem constants
#define BB    128
#define CC    272
#define TT    512
#define DD1   320
#define KC    32      // K-chunk per LDS stage (one mfma K)
#define NCHUNK 9      // ceil(272/32): K zero-padded to 288 (exact)
#define NT    64      // t-tile per block
#define MT    160     // d-tile per block (D1 split in 2)
#define LDA   40      // As row stride, bf16 elems (80 B: 16B-aligned, ideal b128 banks)
#define LDBT  40      // Bs row stride, bf16 elems (80 B: same ideal b128 bank spread)

typedef float  f32x4  __attribute__((ext_vector_type(4)));
typedef __bf16 bf16x4 __attribute__((ext_vector_type(4)));
typedef __bf16 bf16x8 __attribute__((ext_vector_type(8)));

// Raw barrier: orders LDS ops (lgkmcnt(0)) without draining vmcnt — keeps
// register-prefetch global loads in flight across the barrier.
#define BAR() asm volatile("s_waitcnt lgkmcnt(0)\ns_barrier" ::: "memory")

// out[b,d,t] = sum_c W[s_b,d,c] * X[b,c,t]
// Grid (B, T/NT, 2). Block 256 thr / 4 waves as 2(m) x 2(n).
// Double-buffered LDS; chunk k+1 held in regs during compute of k; chunk k+2
// loads issued after the reg->LDS store. One lgkm-only barrier per iter.
// Bs is bf16 [t][c] so the B-fragment is 2x ds_read_b128 (was 16x ds_read_b32
// + 16 cvt from f32 [c][t]). LDS 35.8 KB -> 4 blocks/CU (was 42.5 KB -> 3).
__global__ __launch_bounds__(256, 4)
void subj_conv_mfma(const float* __restrict__ X,
                    const int*   __restrict__ sidx,
                    const float* __restrict__ W,
                    float*       __restrict__ out) {
    const int b  = blockIdx.x;
    const int T0 = blockIdx.y * NT;
    const int d0 = blockIdx.z * MT;
    const int s  = sidx[b];

    __shared__ __align__(16) __bf16 As[2][MT * LDA];   // 2 x 12.5 KB, bf16 [m][kk]
    __shared__ __align__(16) __bf16 Bs[2][NT * LDBT];  // 2 x 5 KB,    bf16 [t][c]

    const int tid  = threadIdx.x;
    const int lane = tid & 63;
    const int wv   = tid >> 6;
    const int wm   = wv & 1;          // m-half (80 rows)
    const int wn   = wv >> 1;         // n-half (32 t)
    const int quad = lane >> 4;
    const int l16  = lane & 15;

    const float* Wb = W + ((size_t)s * DD1 + d0) * CC;
    const float* Xb = X + (size_t)b * CC * TT + T0;

    // A staging map: p<5: m = (tid>>3)+32p, kk = (tid&7)*4
    const int am  = tid >> 3;
    const int akk = (tid & 7) * 4;
    // B staging map: c = c0 + 8*wv + r (r<8), t = lane.
    // Each global_load_dword: 64 lanes x 4B contiguous along t = fully coalesced.
    const float* Xc = Xb + (size_t)(8 * wv) * TT + lane;

    f32x4 acc[5][2];
#pragma unroll
    for (int mt = 0; mt < 5; ++mt) {
        acc[mt][0] = (f32x4){0.f, 0.f, 0.f, 0.f};
        acc[mt][1] = (f32x4){0.f, 0.f, 0.f, 0.f};
    }

    float4 pa[5];
    float  pbx[8];

    // ---- issue global loads for chunk at c0 (no bounds checks: c0+KC <= CC)
    auto load_chunk_full = [&](int c0) {
#pragma unroll
        for (int p = 0; p < 5; ++p)
            pa[p] = *(const float4*)(Wb + (size_t)(am + 32 * p) * CC + c0 + akk);
#pragma unroll
        for (int r = 0; r < 8; ++r)
            pbx[r] = Xc[(size_t)(c0 + r) * TT];
    };

    // ---- guarded variant (last chunk only: c0 = 256, K tail zero-padded)
    auto load_chunk_guard = [&](int c0) {
#pragma unroll
        for (int p = 0; p < 5; ++p) {
            const int c = c0 + akk;                    // mult of 4; float4 stays in-bounds
            float4 v = make_float4(0.f, 0.f, 0.f, 0.f);
            if (c < CC) v = *(const float4*)(Wb + (size_t)(am + 32 * p) * CC + c);
            pa[p] = v;
        }
#pragma unroll
        for (int r = 0; r < 8; ++r) {
            const int c = c0 + 8 * wv + r;
            pbx[r] = (c < CC) ? Xc[(size_t)(c0 + r) * TT] : 0.f;
        }
    };

    // ---- cvt/store regs into LDS buffer `buf`
    auto store_chunk = [&](int buf) {
#pragma unroll
        for (int p = 0; p < 5; ++p) {
            bf16x4 h = {(__bf16)pa[p].x, (__bf16)pa[p].y,
                        (__bf16)pa[p].z, (__bf16)pa[p].w};
            *(bf16x4*)&As[buf][(am + 32 * p) * LDA + akk] = h;   // b64, ideal banks
        }
        bf16x8 hb;
#pragma unroll
        for (int r = 0; r < 8; ++r) hb[r] = (__bf16)pbx[r];
        *(bf16x8*)&Bs[buf][lane * LDBT + 8 * wv] = hb;           // one b128, ideal banks
    };

    // ---- pipeline fill
    load_chunk_full(0);
    store_chunk(0);          // vmcnt wait here (fill cost, once)
    load_chunk_full(KC);     // chunk 1 in flight across barrier
    BAR();

    for (int kc = 0; kc < NCHUNK; ++kc) {
        const int cur = kc & 1;

        // B-frags: element j = X[c0 + quad*8 + j][T0 + tcol] — contiguous in [t][c]
        bf16x8 bfr[2];
#pragma unroll
        for (int nt = 0; nt < 2; ++nt)
            bfr[nt] = *(const bf16x8*)&Bs[cur][(wn * 32 + nt * 16 + l16) * LDBT + quad * 8];

#pragma unroll
        for (int mt = 0; mt < 5; ++mt) {
            bf16x8 af = *(const bf16x8*)&As[cur][(wm * 80 + mt * 16 + l16) * LDA + quad * 8];
#pragma unroll
            for (int nt = 0; nt < 2; ++nt)
                acc[mt][nt] = __builtin_amdgcn_mfma_f32_16x16x32_bf16(
                    af, bfr[nt], acc[mt][nt], 0, 0, 0);
        }

        if (kc + 1 < NCHUNK) {
            store_chunk(1 - cur);                 // chunk kc+1 (vmcnt hidden: issued 1 iter ago)
            if (kc + 2 < NCHUNK) {
                const int c0 = (kc + 2) * KC;
                if (kc + 2 == NCHUNK - 1) load_chunk_guard(c0);
                else                      load_chunk_full(c0);
            }
            BAR();
        }
    }

    // ---- epilogue: D[m = quad*4 + r][n = l16]
#pragma unroll
    for (int mt = 0; mt < 5; ++mt) {
        const int d = d0 + wm * 80 + mt * 16 + quad * 4;
#pragma unroll
        for (int nt = 0; nt < 2; ++nt) {
            float* ob = out + ((size_t)b * DD1 + d) * TT + T0 + wn * 32 + nt * 16 + l16;
#pragma unroll
            for (int r = 0; r < 4; ++r)
                ob[(size_t)r * TT] = acc[mt][nt][r];
        }
    }
}

extern "C" void kernel_launch(void* const* d_in, const int* in_sizes, int n_in,
                              void* d_out, int out_size, void* d_ws, size_t ws_size,
                              hipStream_t stream) {
    const float* X    = (const float*)d_in[0];   // [B, C, T]
    const int*   sidx = (const int*)  d_in[1];   // [B]
    const float* W    = (const float*)d_in[2];   // [S, D1, C]
    float*       out  = (float*)d_out;           // [B, D1, T]

    dim3 grid(BB, TT / NT, 2);   // 128 x 8 x 2 = 2048 blocks
    dim3 block(256);
    subj_conv_mfma<<<grid, block, 0, stream>>>(X, sidx, W, out);
}

// Round 4
// 181.119 us; speedup vs baseline: 1.0172x; 1.0172x over previous
//
#include <hip/hip_runtime.h>

// Problem constants
#define BB    128
#define CC    272
#define TT    512
#define DD1   320
#define KC    32      // K-chunk per LDS stage (one mfma K)
#define NCHUNK 9      // ceil(272/32): K zero-padded to 288 (exact)
#define NT    64      // t-tile per block
#define MT    160     // d-tile per block (D1 split in 2)
#define LDA   40      // As row stride, bf16 elems (80 B: 16B-aligned, ideal b128 banks)
#define LDBT  40      // Bs row stride, bf16 elems (80 B: same ideal b128 bank spread)

typedef float  f32x4  __attribute__((ext_vector_type(4)));
typedef __bf16 bf16x4 __attribute__((ext_vector_type(4)));
typedef __bf16 bf16x8 __attribute__((ext_vector_type(8)));

// Raw barrier: orders LDS ops (lgkmcnt(0)) without draining vmcnt — keeps
// register-prefetch global loads in flight across the barrier.
#define BAR() asm volatile("s_waitcnt lgkmcnt(0)\ns_barrier" ::: "memory")

// out[b,d,t] = sum_c W[s_b,d,c] * X[b,c,t]
// 2048 blocks, 256 thr / 4 waves as 2(m) x 2(n).
// Chunked-XCD mapping: all 16 tiles (8 t-tiles x 2 d-halves) of one b are
// consecutive block ids on one XCD (bid%8 = XCD round-robin), so X[b]
// (557 KB) is L2-resident for all its consumers (~6 b's live/XCD = 3.3 MB).
// 2-deep register prefetch: chunk k+3 issued at iter k, stored at k+2 —
// two iterations of compute hide global-load latency; compiler emits
// counted vmcnt waits on the older set only.
__global__ __launch_bounds__(256, 3)
void subj_conv_mfma(const float* __restrict__ X,
                    const int*   __restrict__ sidx,
                    const float* __restrict__ W,
                    float*       __restrict__ out) {
    const int bid  = blockIdx.x;                 // 0..2047
    // bid = ((b>>3)*16 + tile)*8 + (b&7)  — bijective over 128 b x 16 tiles
    const int b    = (bid & 7) + 8 * (bid >> 7);
    const int tile = (bid >> 3) & 15;
    const int T0   = (tile >> 1) * NT;
    const int d0   = (tile & 1) * MT;
    const int s    = sidx[b];

    __shared__ __align__(16) __bf16 As[2][MT * LDA];   // 2 x 12.5 KB, bf16 [m][kk]
    __shared__ __align__(16) __bf16 Bs[2][NT * LDBT];  // 2 x 5 KB,    bf16 [t][c]

    const int tid  = threadIdx.x;
    const int lane = tid & 63;
    const int wv   = tid >> 6;
    const int wm   = wv & 1;          // m-half (80 rows)
    const int wn   = wv >> 1;         // n-half (32 t)
    const int quad = lane >> 4;
    const int l16  = lane & 15;

    const float* Wb = W + ((size_t)s * DD1 + d0) * CC;
    const float* Xb = X + (size_t)b * CC * TT + T0;

    // A staging map: p<5: m = (tid>>3)+32p, kk = (tid&7)*4
    const int am  = tid >> 3;
    const int akk = (tid & 7) * 4;
    // B staging map: c = c0 + 8*wv + r (r<8), t = lane (fully coalesced dwords)
    const float* Xc = Xb + (size_t)(8 * wv) * TT + lane;

    f32x4 acc[5][2];
#pragma unroll
    for (int mt = 0; mt < 5; ++mt) {
        acc[mt][0] = (f32x4){0.f, 0.f, 0.f, 0.f};
        acc[mt][1] = (f32x4){0.f, 0.f, 0.f, 0.f};
    }

    // Two named register prefetch sets (static alternation — no runtime idx)
    float4 pa0[5], pa1[5];
    float  pb0[8], pb1[8];

    auto load_full = [&](float4 (&pa)[5], float (&pbx)[8], int c0) {
#pragma unroll
        for (int p = 0; p < 5; ++p)
            pa[p] = *(const float4*)(Wb + (size_t)(am + 32 * p) * CC + c0 + akk);
#pragma unroll
        for (int r = 0; r < 8; ++r)
            pbx[r] = Xc[(size_t)(c0 + r) * TT];
    };

    auto load_guard = [&](float4 (&pa)[5], float (&pbx)[8], int c0) {
#pragma unroll
        for (int p = 0; p < 5; ++p) {
            const int c = c0 + akk;                    // mult of 4; float4 stays in-bounds
            float4 v = make_float4(0.f, 0.f, 0.f, 0.f);
            if (c < CC) v = *(const float4*)(Wb + (size_t)(am + 32 * p) * CC + c);
            pa[p] = v;
        }
#pragma unroll
        for (int r = 0; r < 8; ++r) {
            const int c = c0 + 8 * wv + r;
            pbx[r] = (c < CC) ? Xc[(size_t)(c0 + r) * TT] : 0.f;
        }
    };

    auto store_chunk = [&](int buf, const float4 (&pa)[5], const float (&pbx)[8]) {
#pragma unroll
        for (int p = 0; p < 5; ++p) {
            bf16x4 h = {(__bf16)pa[p].x, (__bf16)pa[p].y,
                        (__bf16)pa[p].z, (__bf16)pa[p].w};
            *(bf16x4*)&As[buf][(am + 32 * p) * LDA + akk] = h;   // b64, ~2-way banks (free)
        }
        bf16x8 hb;
#pragma unroll
        for (int r = 0; r < 8; ++r) hb[r] = (__bf16)pbx[r];
        *(bf16x8*)&Bs[buf][lane * LDBT + 8 * wv] = hb;           // one b128, ideal banks
    };

    auto compute = [&](int cur) {
        bf16x8 bfr[2];
#pragma unroll
        for (int nt = 0; nt < 2; ++nt)
            bfr[nt] = *(const bf16x8*)&Bs[cur][(wn * 32 + nt * 16 + l16) * LDBT + quad * 8];
#pragma unroll
        for (int mt = 0; mt < 5; ++mt) {
            bf16x8 af = *(const bf16x8*)&As[cur][(wm * 80 + mt * 16 + l16) * LDA + quad * 8];
#pragma unroll
            for (int nt = 0; nt < 2; ++nt)
                acc[mt][nt] = __builtin_amdgcn_mfma_f32_16x16x32_bf16(
                    af, bfr[nt], acc[mt][nt], 0, 0, 0);
        }
    };

    // ---- pipeline fill: chunks 0,1 loaded; chunk 0 staged; chunk 2 in flight
    load_full(pa0, pb0, 0);
    load_full(pa1, pb1, KC);
    store_chunk(0, pa0, pb0);      // waits only set0 (13 newer loads stay in flight)
    load_full(pa0, pb0, 2 * KC);
    BAR();

    // Invariant at top of iter k: set[(k+1)&1] holds chunk k+1 (arrived or close),
    // set[k&1] holds chunk k+2 (in flight, ~2 iters of slack).
#pragma unroll
    for (int kc = 0; kc < 8; kc += 2) {
        // ---- even iter kc: compute buf0, stage chunk kc+1 from set1
        compute(0);
        store_chunk(1, pa1, pb1);
        if (kc + 3 < NCHUNK) {
            if (kc + 3 == NCHUNK - 1) load_guard(pa1, pb1, (kc + 3) * KC);
            else                      load_full (pa1, pb1, (kc + 3) * KC);
        }
        BAR();
        // ---- odd iter kc+1: compute buf1, stage chunk kc+2 from set0
        compute(1);
        if (kc + 2 < NCHUNK) {
            store_chunk(0, pa0, pb0);
            if (kc + 4 < NCHUNK) {
                if (kc + 4 == NCHUNK - 1) load_guard(pa0, pb0, (kc + 4) * KC);
                else                      load_full (pa0, pb0, (kc + 4) * KC);
            }
            BAR();
        }
    }
    compute(0);   // chunk 8 (kc = 8, buf0)

    // ---- epilogue: D[m = quad*4 + r][n = l16]
#pragma unroll
    for (int mt = 0; mt < 5; ++mt) {
        const int d = d0 + wm * 80 + mt * 16 + quad * 4;
#pragma unroll
        for (int nt = 0; nt < 2; ++nt) {
            float* ob = out + ((size_t)b * DD1 + d) * TT + T0 + wn * 32 + nt * 16 + l16;
#pragma unroll
            for (int r = 0; r < 4; ++r)
                ob[(size_t)r * TT] = acc[mt][nt][r];
        }
    }
}

extern "C" void kernel_launch(void* const* d_in, const int* in_sizes, int n_in,
                              void* d_out, int out_size, void* d_ws, size_t ws_size,
                              hipStream_t stream) {
    const float* X    = (const float*)d_in[0];   // [B, C, T]
    const int*   sidx = (const int*)  d_in[1];   // [B]
    const float* W    = (const float*)d_in[2];   // [S, D1, C]
    float*       out  = (float*)d_out;           // [B, D1, T]

    dim3 grid(BB * (TT / NT) * 2);   // 2048 blocks, chunked-XCD decode in-kernel
    dim3 block(256);
    subj_conv_mfma<<<grid, block, 0, stream>>>(X, sidx, W, out);
}

// Round 5
// 172.193 us; speedup vs baseline: 1.0700x; 1.0518x over previous
//
#include <hip/hip_runtime.h>

// Problem constants
#define BB    128
#define CC    272
#define TT    512
#define DD1   320
#define KC    32      // K-chunk per LDS stage (one mfma K)
#define NCHUNK 9      // ceil(272/32): K zero-padded to 288 (exact)
#define NT    64      // t-tile per block
#define MT    160     // d-tile per block (D1 split in 2)
#define LDA   40      // As row stride, bf16 elems (80 B: 16B-aligned, free-read banks)
#define LDB2  66      // Bs row stride, f32 elems (264 B: 8B-aligned, free-read banks)
#define LDE   20      // epilogue tile row stride, f32 (2-way write banks = free)

typedef float  f32x4  __attribute__((ext_vector_type(4)));
typedef __bf16 bf16x4 __attribute__((ext_vector_type(4)));
typedef __bf16 bf16x8 __attribute__((ext_vector_type(8)));

// Raw barrier: orders LDS ops (lgkmcnt(0)) without draining vmcnt — keeps
// register-prefetch global loads in flight across the barrier.
#define BAR() asm volatile("s_waitcnt lgkmcnt(0)\ns_barrier" ::: "memory")
#define LGKM0() asm volatile("s_waitcnt lgkmcnt(0)" ::: "memory")

// out[b,d,t] = sum_c W[s_b,d,c] * X[b,c,t]
// 2048 blocks (1D, XCD-chunked decode), 256 thr / 4 waves as 2(m) x 2(n).
// Base = R0 structure (66 us measured): f32 [c][t] Bs, bf16 [m][k] As,
// 1-deep register prefetch, lgkm-only barrier per iter.
// + XCD swizzle: all 16 tiles of one b consecutive on one XCD (FETCH 88->51MB, R4-proven).
// + float4 epilogue: 4x4 cross-lane transpose through padded LDS tile;
//   40 scalar stores/thread -> 10 dwordx4 (VMEM wave-instruction diet).
__global__ __launch_bounds__(256, 4)
void subj_conv_mfma(const float* __restrict__ X,
                    const int*   __restrict__ sidx,
                    const float* __restrict__ W,
                    float*       __restrict__ out) {
    const int bid  = blockIdx.x;                 // 0..2047
    // bid = ((b>>3)*16 + tile)*8 + (b&7)  — bijective over 128 b x 16 tiles
    const int b    = (bid & 7) + 8 * (bid >> 7);
    const int tile = (bid >> 3) & 15;
    const int T0   = (tile >> 1) * NT;
    const int d0   = (tile & 1) * MT;
    const int s    = sidx[b];

    __shared__ __align__(16) __bf16 As[2][MT * LDA];    // 2 x 12.8 KB, bf16 [m][kk]
    __shared__ __align__(16) float  Bs[2][KC * LDB2];   // 2 x 8.45 KB, fp32 natural [c][t]

    const int tid  = threadIdx.x;
    const int lane = tid & 63;
    const int wv   = tid >> 6;
    const int wm   = wv & 1;          // m-half (80 rows)
    const int wn   = wv >> 1;         // n-half (32 t)
    const int quad = lane >> 4;
    const int l16  = lane & 15;

    const float* Wb = W + ((size_t)s * DD1 + d0) * CC;
    const float* Xb = X + (size_t)b * CC * TT + T0;

    // A staging map: p<5: m = (tid>>3)+32p, kk = (tid&7)*4
    const int am  = tid >> 3;
    const int akk = (tid & 7) * 4;
    // B staging map: p<2: c-row = (tid>>4)+16p, t = (tid&15)*4
    const int bcr = tid >> 4;
    const int bt  = (tid & 15) * 4;

    f32x4 acc[5][2];
#pragma unroll
    for (int mt = 0; mt < 5; ++mt) {
        acc[mt][0] = (f32x4){0.f, 0.f, 0.f, 0.f};
        acc[mt][1] = (f32x4){0.f, 0.f, 0.f, 0.f};
    }

    float4 pa[5];
    float4 pb[2];

    // ---- issue global loads for chunk at c0 into pa/pb (all dwordx4)
    auto load_chunk = [&](int c0) {
#pragma unroll
        for (int p = 0; p < 5; ++p) {
            const int m = am + 32 * p;
            const int c = c0 + akk;
            float4 v = make_float4(0.f, 0.f, 0.f, 0.f);
            if (c < CC) v = *(const float4*)(Wb + (size_t)m * CC + c);
            pa[p] = v;
        }
#pragma unroll
        for (int p = 0; p < 2; ++p) {
            const int c = c0 + bcr + 16 * p;
            float4 v = make_float4(0.f, 0.f, 0.f, 0.f);
            if (c < CC) v = *(const float4*)(Xb + (size_t)c * TT + bt);
            pb[p] = v;
        }
    };

    // ---- cvt/store regs into LDS buffer `buf`
    auto store_chunk = [&](int buf) {
#pragma unroll
        for (int p = 0; p < 5; ++p) {
            const int m = am + 32 * p;
            bf16x4 h = {(__bf16)pa[p].x, (__bf16)pa[p].y,
                        (__bf16)pa[p].z, (__bf16)pa[p].w};
            *(bf16x4*)&As[buf][m * LDA + akk] = h;       // b64, ~2-way banks
        }
#pragma unroll
        for (int p = 0; p < 2; ++p) {
            const int cr = bcr + 16 * p;
            float* row = &Bs[buf][cr * LDB2 + bt];       // natural layout, b64 x2
            *(float2*)(row + 0) = make_float2(pb[p].x, pb[p].y);
            *(float2*)(row + 2) = make_float2(pb[p].z, pb[p].w);
        }
    };

    // ---- pipeline fill
    load_chunk(0);
    store_chunk(0);          // vmcnt wait here (fill cost, once)
    load_chunk(KC);          // chunk 1 in flight across barrier
    BAR();

    for (int kc = 0; kc < NCHUNK; ++kc) {
        const int cur = kc & 1;

        // B-frags: gather 8 f32 per frag from natural [c][t] (2-way banks, free)
        bf16x8 bfr[2];
#pragma unroll
        for (int nt = 0; nt < 2; ++nt) {
            const int tcol = wn * 32 + nt * 16 + l16;
            bf16x8 h;
#pragma unroll
            for (int j = 0; j < 8; ++j)
                h[j] = (__bf16)Bs[cur][(quad * 8 + j) * LDB2 + tcol];
            bfr[nt] = h;
        }

#pragma unroll
        for (int mt = 0; mt < 5; ++mt) {
            bf16x8 af = *(const bf16x8*)&As[cur][(wm * 80 + mt * 16 + l16) * LDA + quad * 8];
#pragma unroll
            for (int nt = 0; nt < 2; ++nt)
                acc[mt][nt] = __builtin_amdgcn_mfma_f32_16x16x32_bf16(
                    af, bfr[nt], acc[mt][nt], 0, 0, 0);
        }

        if (kc + 1 < NCHUNK) {
            store_chunk(1 - cur);                 // chunk kc+1 (vmcnt hidden: issued 1 iter ago)
            if (kc + 2 < NCHUNK) load_chunk((kc + 2) * KC);
            BAR();
        }
    }

    // ---- epilogue: 4x4 cross-lane transpose via LDS, store float4 along t.
    // Per-wave region in (reused) As space: 5 tiles of 16 x LDE f32 = 6400 B;
    // 4 waves x 6400 = 25600 B = sizeof(As) exactly. Barrier first: waves may
    // still be reading As for the last chunk's compute.
    BAR();
    float* tw = (float*)As + wv * (5 * 16 * LDE);
#pragma unroll
    for (int nt = 0; nt < 2; ++nt) {
        if (nt) LGKM0();   // prior batch's reads retired before overwrite
#pragma unroll
        for (int mt = 0; mt < 5; ++mt)
#pragma unroll
            for (int r = 0; r < 4; ++r)
                tw[mt * (16 * LDE) + (quad * 4 + r) * LDE + l16] = acc[mt][nt][r];
        LGKM0();           // cross-lane RAW: writes visible before reads
#pragma unroll
        for (int mt = 0; mt < 5; ++mt) {
            f32x4 v = *(const f32x4*)&tw[mt * (16 * LDE) + l16 * LDE + quad * 4];
            float* op = out + ((size_t)b * DD1 + d0 + wm * 80 + mt * 16 + l16) * TT
                            + T0 + wn * 32 + nt * 16 + quad * 4;
            *(f32x4*)op = v;
        }
    }
}

extern "C" void kernel_launch(void* const* d_in, const int* in_sizes, int n_in,
                              void* d_out, int out_size, void* d_ws, size_t ws_size,
                              hipStream_t stream) {
    const float* X    = (const float*)d_in[0];   // [B, C, T]
    const int*   sidx = (const int*)  d_in[1];   // [B]
    const float* W    = (const float*)d_in[2];   // [S, D1, C]
    float*       out  = (float*)d_out;           // [B, D1, T]

    dim3 grid(BB * (TT / NT) * 2);   // 2048 blocks, XCD-chunked decode in-kernel
    dim3 block(256);
    subj_conv_mfma<<<grid, block, 0, stream>>>(X, sidx, W, out);
}